// Round 1
// 1274.141 us; speedup vs baseline: 1.4460x; 1.4460x over previous
//
#include <hip/hip_runtime.h>
#include <hip/hip_bf16.h>
#include <stdint.h>

#define B_  16
#define T_  2048
#define C_  512
#define H_  256
#define NO_ 5

typedef _Float16 half8 __attribute__((ext_vector_type(8)));
typedef float    f32x4 __attribute__((ext_vector_type(4)));

struct Keys { uint32_t k0[NO_]; uint32_t k1[NO_]; };

// ---------------- threefry2x32 (JAX rotation/injection schedule) ----------------
__device__ __forceinline__ uint32_t tf_xor(uint32_t ks0, uint32_t ks1, uint32_t ctr) {
  uint32_t ks2 = ks0 ^ ks1 ^ 0x1BD11BDAu;
  uint32_t x0 = ks0;        // counts_hi (=0) + ks0
  uint32_t x1 = ctr + ks1;  // counts_lo + ks1
#define TFR(r) { x0 += x1; x1 = (x1 << r) | (x1 >> (32 - r)); x1 ^= x0; }
  TFR(13) TFR(15) TFR(26) TFR(6)   x0 += ks1; x1 += ks2 + 1u;
  TFR(17) TFR(29) TFR(16) TFR(24)  x0 += ks2; x1 += ks0 + 2u;
  TFR(13) TFR(15) TFR(26) TFR(6)   x0 += ks0; x1 += ks1 + 3u;
  TFR(17) TFR(29) TFR(16) TFR(24)  x0 += ks1; x1 += ks2 + 4u;
  TFR(13) TFR(15) TFR(26) TFR(6)   x0 += ks2; x1 += ks0 + 5u;
#undef TFR
  return x0 ^ x1;  // partitionable 32-bit output combine
}

// XLA ErfInv f32 (Giles poly). w = -log1p(-x^2) replaced by factored hw log:
// (1-x)(1+x) has no cancellation for |x|<1, so v_log_f32 (1-ulp) is safe;
// saves the ~30-inst libm log1pf. pb path taken per-wave only when some lane
// has w>=5 (P~0.33%/lane -> ~80% of waves skip it; branch cost is scalar-pipe).
__device__ __forceinline__ float erfinv_f(float x) {
  float w = -__logf((1.0f - x) * (1.0f + x));
  float wa = w - 2.5f;
  float pa = 2.81022636e-08f;
  pa = __fmaf_rn(pa, wa, 3.43273939e-07f);
  pa = __fmaf_rn(pa, wa, -3.5233877e-06f);
  pa = __fmaf_rn(pa, wa, -4.39150654e-06f);
  pa = __fmaf_rn(pa, wa, 0.00021858087f);
  pa = __fmaf_rn(pa, wa, -0.00125372503f);
  pa = __fmaf_rn(pa, wa, -0.00417768164f);
  pa = __fmaf_rn(pa, wa, 0.246640727f);
  pa = __fmaf_rn(pa, wa, 1.50140941f);
  float p = pa;
  if (__builtin_expect(!(w < 5.0f), 0)) {
    float wb = __fsqrt_rn(w) - 3.0f;
    float pb = -0.000200214257f;
    pb = __fmaf_rn(pb, wb, 0.000100950558f);
    pb = __fmaf_rn(pb, wb, 0.00134934322f);
    pb = __fmaf_rn(pb, wb, -0.00367342844f);
    pb = __fmaf_rn(pb, wb, 0.00573950773f);
    pb = __fmaf_rn(pb, wb, -0.0076224613f);
    pb = __fmaf_rn(pb, wb, 0.00943887047f);
    pb = __fmaf_rn(pb, wb, 1.00167406f);
    pb = __fmaf_rn(pb, wb, 2.83297682f);
    p = pb;
  }
  return p * x;
}

__device__ __forceinline__ float normal_from_ctr(uint32_t k0, uint32_t k1, uint32_t ctr) {
  uint32_t bits = tf_xor(k0, k1, ctr);
  float f = __uint_as_float((bits >> 9) | 0x3f800000u) - 1.0f;   // [0,1)
  float u = __fadd_rn(__fmul_rn(f, 2.0f), -0.99999994f);         // f*(hi-lo)+lo, hi-lo==2.0f exactly
  u = fmaxf(-0.99999994f, u);
  return __fmul_rn(1.41421354f, erfinv_f(u));
}

// ---------------- K0: zero smooth accumulators ----------------
__global__ void k_zero(float* acc) {
  if (threadIdx.x < B_ * NO_) acc[threadIdx.x] = 0.f;
}

// ---------------- Kt: w1 [5][512][256] f32 -> w1T [5][256][512] f16 ----------------
__global__ __launch_bounds__(256) void k_tr(const float* __restrict__ w1, _Float16* __restrict__ w1T) {
  __shared__ float tl[32][33];
  int tx = threadIdx.x & 31, ty = threadIdx.x >> 5;
  int head = blockIdx.x >> 7, r = blockIdx.x & 127, kb = r >> 3, hb = r & 7;
  const float* src = w1 + ((size_t)head * C_ + kb * 32) * H_ + hb * 32;
  #pragma unroll
  for (int q = 0; q < 4; q++) { int kr = ty + q * 8; tl[kr][tx] = src[(size_t)kr * H_ + tx]; }
  __syncthreads();
  _Float16* dst = w1T + ((size_t)head * H_ + hb * 32) * C_ + kb * 32;
  #pragma unroll
  for (int q = 0; q < 4; q++) { int hr = ty + q * 8; dst[(size_t)hr * C_ + tx] = (_Float16)tl[tx][hr]; }
}

// ---------------- Kx: x f32 -> f16 once (A re-read x5 by heads; 34MB f16 is L3-resident) ----
__global__ __launch_bounds__(256) void k_xcast(const float* __restrict__ x, _Float16* __restrict__ xh) {
  size_t idx = ((size_t)blockIdx.x * 256 + threadIdx.x) * 8;
  float4 a0 = *(const float4*)(x + idx);
  float4 a1 = *(const float4*)(x + idx + 4);
  half8 h;
  h[0] = (_Float16)a0.x; h[1] = (_Float16)a0.y; h[2] = (_Float16)a0.z; h[3] = (_Float16)a0.w;
  h[4] = (_Float16)a1.x; h[5] = (_Float16)a1.y; h[6] = (_Float16)a1.z; h[7] = (_Float16)a1.w;
  *(half8*)(xh + idx) = h;
}

// ---------------- K1: fused f16-MFMA GEMM + gelu + mu_sig + smooth partials ----------------
// block: 64 rows (of B*T) x 256 cols (full H), head = blockIdx/512
template<int USE_XH>
__global__ __launch_bounds__(256) void k_gemm(const float* __restrict__ x,
                                              const _Float16* __restrict__ xh,
                                              const _Float16* __restrict__ w1T,
                                              const float* __restrict__ b1g,
                                              const float* __restrict__ w2g,
                                              const float* __restrict__ b2g,
                                              const float* __restrict__ wsg,
                                              float* __restrict__ mu_sigs,
                                              float* __restrict__ acc) {
  __shared__ _Float16 Alds[64 * 40];    // padded stride 40 halves (80B) -> 2-way max on b128
  __shared__ _Float16 Blds[256 * 40];
  __shared__ float red3[64 * 2 * 3];
  const int bid = blockIdx.x;
  const int head = bid >> 9;
  const int m0 = (bid & 511) << 6;
  const int tid = threadIdx.x;
  const int wave = tid >> 6, lane = tid & 63;
  const int wm = wave >> 1, wn = wave & 1;       // wave covers rows wm*32..+32, cols wn*128..+128
  const int col = lane & 15, quad = lane >> 4;

  f32x4 accv[2][8];
  #pragma unroll
  for (int a = 0; a < 2; a++)
    #pragma unroll
    for (int c = 0; c < 8; c++) accv[a][c] = (f32x4){0.f, 0.f, 0.f, 0.f};

  const float* xA = x + (size_t)m0 * C_;
  const _Float16* xAh = xh + (size_t)m0 * C_;
  const _Float16* wB = w1T + (size_t)head * H_ * C_;
  const int arow = tid >> 2, aseg = tid & 3;

  for (int ks = 0; ks < 16; ++ks) {
    const int k0 = ks << 5;
    // stage A: 64 rows x 32 k
    if constexpr (USE_XH) {
      half8 ah = *(const half8*)(xAh + (size_t)arow * C_ + k0 + aseg * 8);
      *(half8*)(&Alds[arow * 40 + aseg * 8]) = ah;
    } else {
      float4 a0 = *(const float4*)(xA + (size_t)arow * C_ + k0 + aseg * 8);
      float4 a1 = *(const float4*)(xA + (size_t)arow * C_ + k0 + aseg * 8 + 4);
      half8 ah;
      ah[0] = (_Float16)a0.x; ah[1] = (_Float16)a0.y; ah[2] = (_Float16)a0.z; ah[3] = (_Float16)a0.w;
      ah[4] = (_Float16)a1.x; ah[5] = (_Float16)a1.y; ah[6] = (_Float16)a1.z; ah[7] = (_Float16)a1.w;
      *(half8*)(&Alds[arow * 40 + aseg * 8]) = ah;
    }
    // stage B: 256 n-rows x 32 k (w1T already [n][k] f16)
    const _Float16* bsrc = wB + (size_t)tid * C_ + k0;
    half8 bv0 = *(const half8*)(bsrc + 0);
    half8 bv1 = *(const half8*)(bsrc + 8);
    half8 bv2 = *(const half8*)(bsrc + 16);
    half8 bv3 = *(const half8*)(bsrc + 24);
    *(half8*)(&Blds[tid * 40 + 0])  = bv0;
    *(half8*)(&Blds[tid * 40 + 8])  = bv1;
    *(half8*)(&Blds[tid * 40 + 16]) = bv2;
    *(half8*)(&Blds[tid * 40 + 24]) = bv3;
    __syncthreads();
    half8 af[2];
    #pragma unroll
    for (int mt = 0; mt < 2; ++mt)
      af[mt] = *(const half8*)(&Alds[(wm * 32 + mt * 16 + col) * 40 + quad * 8]);
    #pragma unroll
    for (int nt = 0; nt < 8; ++nt) {
      half8 bf = *(const half8*)(&Blds[(wn * 128 + nt * 16 + col) * 40 + quad * 8]);
      accv[0][nt] = __builtin_amdgcn_mfma_f32_16x16x32_f16(af[0], bf, accv[0][nt], 0, 0, 0);
      accv[1][nt] = __builtin_amdgcn_mfma_f32_16x16x32_f16(af[1], bf, accv[1][nt], 0, 0, 0);
    }
    __syncthreads();
  }

  // epilogue: gelu + per-row dots with w2[:,0], w2[:,1], ws
  float b1h[8], w2c0[8], w2c1[8], wsc[8];
  #pragma unroll
  for (int nt = 0; nt < 8; ++nt) {
    int ng = wn * 128 + nt * 16 + col;
    b1h[nt] = b1g[head * H_ + ng];
    float2 wv = ((const float2*)w2g)[ng];
    w2c0[nt] = wv.x; w2c1[nt] = wv.y;
    wsc[nt] = wsg[ng];
  }
  #pragma unroll
  for (int mt = 0; mt < 2; ++mt) {
    #pragma unroll
    for (int r = 0; r < 4; ++r) {
      float hm = 0.f, hs = 0.f, hw = 0.f;
      #pragma unroll
      for (int nt = 0; nt < 8; ++nt) {
        float a = accv[mt][nt][r] + b1h[nt];
        float t = a * 0.70710678f;                 // a/sqrt2 as mul (<=1ulp vs div)
        float h = 0.5f * (a * (erff(t) + 1.0f));   // exact gelu
        hm = __fmaf_rn(h, w2c0[nt], hm);
        hs = __fmaf_rn(h, w2c1[nt], hs);
        hw = __fmaf_rn(h, wsc[nt], hw);
      }
      #pragma unroll
      for (int mk = 1; mk < 16; mk <<= 1) {
        hm += __shfl_xor(hm, mk);
        hs += __shfl_xor(hs, mk);
        hw += __shfl_xor(hw, mk);
      }
      if (col == 0) {
        int row = wm * 32 + mt * 16 + quad * 4 + r;
        red3[(row * 2 + wn) * 3 + 0] = hm;
        red3[(row * 2 + wn) * 3 + 1] = hs;
        red3[(row * 2 + wn) * 3 + 2] = hw;
      }
    }
  }
  __syncthreads();
  if (tid < 64) {
    int mg = m0 + tid;
    float mv = red3[(tid * 2 + 0) * 3 + 0] + red3[(tid * 2 + 1) * 3 + 0] + b2g[0];
    float sv = red3[(tid * 2 + 0) * 3 + 1] + red3[(tid * 2 + 1) * 3 + 1] + b2g[1];
    mu_sigs[((size_t)mg * NO_ + head) * 2 + 0] = mv;
    mu_sigs[((size_t)mg * NO_ + head) * 2 + 1] = sv;
    float pw = red3[(tid * 2 + 0) * 3 + 2] + red3[(tid * 2 + 1) * 3 + 2];
    #pragma unroll
    for (int mk = 1; mk < 64; mk <<= 1) pw += __shfl_xor(pw, mk);
    if (tid == 0) atomicAdd(&acc[(m0 >> 11) * NO_ + head], pw);
  }
}

// ---------------- K2: smooths -> normalized Gaussian taps ----------------
__global__ void k_smooth(const float* __restrict__ acc, const float* __restrict__ bs,
                         float* __restrict__ kker) {
  int tid = threadIdx.x;
  if (tid >= B_ * NO_) return;
  float s = acc[tid] * (1.0f / (float)T_) + bs[0];
  float var = __fadd_rn(__fmul_rn(s, s), 1e-6f);
  float kv[17]; float sum = 0.f;
  #pragma unroll
  for (int j = 0; j < 17; j++) {
    float tj = (float)(j - 8);
    kv[j] = expf(__fdiv_rn(-0.5f * tj * tj, var));
    sum += kv[j];
  }
  #pragma unroll
  for (int j = 0; j < 17; j++) kker[tid * 17 + j] = __fdiv_rn(kv[j], sum);
}

// ---------------- K3: noise gen + 17-tap smooth ----------------
// Circular window, 17-phase fully-unrolled inner loop:
//  - all win[] indices are compile-time constants -> pure register rotation,
//    zero shift-movs per step (was 16 v_mov/output).
//  - steady-state taps need only the UPPER reflect (tp>=9); prologue only LOWER.
__global__ __launch_bounds__(256) void k_noise(const float* __restrict__ mu_sigs,
                                               const float* __restrict__ kker,
                                               float* __restrict__ out, Keys keys) {
  int bid = blockIdx.x;
  int i, bstart;
  if (bid < 8)        { i = 0; bstart = 0; }
  else if (bid < 40)  { i = 1; bstart = 8; }
  else if (bid < 168) { i = 2; bstart = 40; }
  else if (bid < 680) { i = 3; bstart = 168; }
  else                { i = 4; bstart = 680; }
  const int lg = 4 + 2 * i;                 // log2(S*S)
  int g = (bid - bstart) * 256 + threadIdx.x;
  int s = g & ((1 << lg) - 1);
  int rest = g >> lg;
  int chunk = rest & 7;
  int b = rest >> 3;
  int t0 = chunk << 8;                      // 256-t chunks
  uint32_t key0 = keys.k0[i], key1 = keys.k1[i];
  const size_t OFF0[5] = {0ul, 524288ul, 2621440ul, 11010048ul, 44564480ul};
  float kt[17];
  {
    const float* kp = kker + (b * NO_ + i) * 17;
    #pragma unroll
    for (int j = 0; j < 17; j++) kt[j] = kp[j];
  }
  const float2* msp = (const float2*)mu_sigs + (size_t)(b * T_) * NO_ + i;
  const uint32_t cbase = ((uint32_t)b << (11 + lg)) + (uint32_t)s;  // == ((b<<11)+tr)<<lg + s with tr<2048
  auto noise = [&](int tr) -> float {
    uint32_t ctr = cbase + ((uint32_t)tr << lg);
    float e = normal_from_ctr(key0, key1, ctr);
    float2 ms = msp[(size_t)tr * NO_];
    return __fadd_rn(ms.x, __fmul_rn(ms.y, e));   // mu + sig*eps (unfused, matches ref)
  };

  float win[17];
  #pragma unroll
  for (int j = 0; j < 17; ++j) {
    int tp = t0 - 8 + j;
    int tr = tp < 0 ? -tp : tp;               // lower reflect only (tp <= 1800 here)
    win[j] = noise(tr);
  }
  float* op = out + OFF0[i] + (((size_t)((b << 11) + t0)) << lg) + s;
  const int stride = 1 << lg;
  // 256 steps = 15 * 17 + 1. Invariant before step m: win[(m+j)%17] = n(t0+m-8+j).
  #pragma unroll 1
  for (int blk = 0; blk < 15; ++blk) {
    const int tb = t0 + blk * 17 + 9;
    #pragma unroll
    for (int u = 0; u < 17; ++u) {
      float o = 0.f;
      #pragma unroll
      for (int j = 0; j < 17; ++j)
        o = __fmaf_rn(kt[j], win[(u + j) % 17], o);
      *op = o; op += stride;
      int tp = tb + u;
      int tr = tp > T_ - 1 ? 2 * (T_ - 1) - tp : tp;  // upper reflect only (tp >= 9)
      win[u] = noise(tr);                              // overwrite oldest slot
    }
  }
  { // final step m=255 (255%17==0): no new tap needed
    float o = 0.f;
    #pragma unroll
    for (int j = 0; j < 17; ++j) o = __fmaf_rn(kt[j], win[j], o);
    *op = o;
  }
}

// ---------------- host ----------------
static void h_tf(uint32_t k0, uint32_t k1, uint32_t& x0, uint32_t& x1) {
  uint32_t ks2 = k0 ^ k1 ^ 0x1BD11BDAu;
  x0 += k0; x1 += k1;
  auto rnd = [&](int r) { x0 += x1; x1 = (x1 << r) | (x1 >> (32 - r)); x1 ^= x0; };
  rnd(13); rnd(15); rnd(26); rnd(6);   x0 += k1;  x1 += ks2 + 1u;
  rnd(17); rnd(29); rnd(16); rnd(24);  x0 += ks2; x1 += k0 + 2u;
  rnd(13); rnd(15); rnd(26); rnd(6);   x0 += k0;  x1 += k1 + 3u;
  rnd(17); rnd(29); rnd(16); rnd(24);  x0 += k1;  x1 += ks2 + 4u;
  rnd(13); rnd(15); rnd(26); rnd(6);   x0 += ks2; x1 += k0 + 5u;
}

extern "C" void kernel_launch(void* const* d_in, const int* in_sizes, int n_in,
                              void* d_out, int out_size, void* d_ws, size_t ws_size,
                              hipStream_t stream) {
  const float* x   = (const float*)d_in[0];
  const float* w1  = (const float*)d_in[1];
  const float* b1  = (const float*)d_in[2];
  const float* w2  = (const float*)d_in[3];
  const float* b2  = (const float*)d_in[4];
  const float* wsv = (const float*)d_in[5];
  const float* bs  = (const float*)d_in[6];
  float* out = (float*)d_out;

  float* wsf = (float*)d_ws;
  float* mu_sigs = wsf;                          // 327680 floats
  float* acc     = wsf + 327680;                 // 80
  float* kker    = wsf + 327760;                 // 1360
  _Float16* w1T  = (_Float16*)(wsf + 329120);    // 655360 halves (byte 1,316,480; 16B-aligned)
  _Float16* xh   = (_Float16*)((char*)d_ws + 2627200);  // 16,777,216 halves (33.55MB)
  const size_t WS_NEED_XH = 2627200ull + 33554432ull;   // 36,181,632 B
  const bool use_xh = ws_size >= WS_NEED_XH;

  // fold_in(key(1), i): key data = (0,1); count = (0,i)
  Keys keys;
  for (int i = 0; i < NO_; i++) {
    uint32_t x0 = 0u, x1 = (uint32_t)i;
    h_tf(0u, 1u, x0, x1);
    keys.k0[i] = x0; keys.k1[i] = x1;
  }

  k_zero<<<dim3(1), dim3(128), 0, stream>>>(acc);
  k_tr<<<dim3(640), dim3(256), 0, stream>>>(w1, w1T);
  if (use_xh) {
    k_xcast<<<dim3(8192), dim3(256), 0, stream>>>(x, xh);
    k_gemm<1><<<dim3(2560), dim3(256), 0, stream>>>(x, xh, w1T, b1, w2, b2, wsv, mu_sigs, acc);
  } else {
    k_gemm<0><<<dim3(2560), dim3(256), 0, stream>>>(x, xh, w1T, b1, w2, b2, wsv, mu_sigs, acc);
  }
  k_smooth<<<dim3(1), dim3(128), 0, stream>>>(acc, bs, kker);
  k_noise<<<dim3(2728), dim3(256), 0, stream>>>(mu_sigs, kker, out, keys);
}